// Round 11
// baseline (960.337 us; speedup 1.0000x reference)
//
#include <hip/hip_runtime.h>
#include <hip/hip_cooperative_groups.h>

namespace cg = cooperative_groups;

#define NEG_SLOPE 0.2f
#define LN_EPS 1e-5f
#define DMAX 128          // degree cap for the counting sort
#define CGRID 1024        // cooperative grid (4 blocks/CU x 256 CU, co-resident)

typedef __attribute__((ext_vector_type(8))) short bf16x8;
typedef __attribute__((ext_vector_type(4))) float f32x4;

__device__ inline unsigned short f2bf(float f) {
    unsigned u = __float_as_uint(f);
    unsigned r = u + 0x7FFFu + ((u >> 16) & 1u);   // round-to-nearest-even
    return (unsigned short)(r >> 16);
}

__device__ inline void unpack8(uint4 u, float* f) {
    f[0] = __uint_as_float(u.x << 16);
    f[1] = __uint_as_float(u.x & 0xFFFF0000u);
    f[2] = __uint_as_float(u.y << 16);
    f[3] = __uint_as_float(u.y & 0xFFFF0000u);
    f[4] = __uint_as_float(u.z << 16);
    f[5] = __uint_as_float(u.z & 0xFFFF0000u);
    f[6] = __uint_as_float(u.w << 16);
    f[7] = __uint_as_float(u.w & 0xFFFF0000u);
}

// ---------------- cooperative CSR + degree-sort + W-cast (one launch) ----------------
// Phases (grid.sync between): 0 zero counters + Wt transpose-cast; 1 rank
// (atomicAdd, counters padded to 64B lines); 2 block partial sums; 3 rowptr
// (scan of 1024 partials + chunk scan); 4 place (atomic-free) + degree hist;
// 5 bucket scan + scatter perm (nodes sorted by degree so the 4 nodes
// co-scheduled in an agg wave have equal degree -> no loop divergence).

__global__ __launch_bounds__(256) void csr_coop(
    const int* __restrict__ src, const int* __restrict__ dst,
    const float* __restrict__ ew, int* __restrict__ counts, int* __restrict__ rank,
    int* __restrict__ bsum, int* __restrict__ rowptr, unsigned* __restrict__ edge_p,
    int* __restrict__ deghist, int* __restrict__ dcur, int* __restrict__ perm,
    int n, int E,
    const float* __restrict__ W0, const float* __restrict__ W1,
    const float* __restrict__ W2, unsigned short* __restrict__ Wt0,
    unsigned short* __restrict__ Wt1, unsigned short* __restrict__ Wt2) {
    cg::grid_group grid = cg::this_grid();
    __shared__ int sb[1280];
    const int T = gridDim.x * 256;
    const int gtid = blockIdx.x * 256 + threadIdx.x;
    const int t = threadIdx.x;

    // phase 0: zero counters; transpose-cast the three W matrices
    for (int i = gtid; i < n * 16; i += T) counts[i] = 0;
    for (int i = gtid; i < (DMAX + 1) * 16; i += T) { deghist[i] = 0; dcur[i] = 0; }
    for (int i = gtid; i < 320 * 128; i += T) {
        int row = i >> 7, k = i & 127;
        if (row < 128) Wt0[row * 128 + k] = f2bf(W0[k * 128 + row]);
        else if (row < 256) Wt1[(row - 128) * 128 + k] = f2bf(W1[k * 128 + (row - 128)]);
        else Wt2[(row - 256) * 128 + k] = f2bf(W2[k * 64 + (row - 256)]);
    }
    grid.sync();

    // phase 1: rank = old count
    for (int i = gtid; i < E; i += T) rank[i] = atomicAdd(&counts[dst[i] * 16], 1);
    grid.sync();

    // phase 2: per-block partial sum of its chunk of counts
    const int CH = (n + gridDim.x - 1) / gridDim.x;   // <=256 required
    {
        int i = blockIdx.x * CH + t;
        int c = (t < CH && i < n) ? counts[i * 16] : 0;
        sb[t] = c;
        __syncthreads();
        for (int off = 128; off > 0; off >>= 1) {
            int v = (t < off) ? sb[t + off] : 0;
            __syncthreads();
            if (t < off) sb[t] += v;
            __syncthreads();
        }
        if (t == 0) bsum[blockIdx.x] = sb[0];
    }
    grid.sync();

    // phase 3: rowptr = exclusive scan (block offset from scanning all partials)
    {
        int* elems = sb;
        int* ps = sb + 1024;
        int l[4];
        int lsum = 0;
        #pragma unroll
        for (int k = 0; k < 4; ++k) {
            int idx = t * 4 + k;
            l[k] = (idx < (int)gridDim.x) ? bsum[idx] : 0;
            lsum += l[k];
        }
        ps[t] = lsum;
        __syncthreads();
        for (int off = 1; off < 256; off <<= 1) {
            int v = (t >= off) ? ps[t - off] : 0;
            __syncthreads();
            ps[t] += v;
            __syncthreads();
        }
        int ebase = ps[t] - lsum;
        elems[t * 4 + 0] = ebase;
        elems[t * 4 + 1] = ebase + l[0];
        elems[t * 4 + 2] = ebase + l[0] + l[1];
        elems[t * 4 + 3] = ebase + l[0] + l[1] + l[2];
        __syncthreads();
        int boff = elems[blockIdx.x];
        __syncthreads();
        int i = blockIdx.x * CH + t;
        int c = (t < CH && i < n) ? counts[i * 16] : 0;
        sb[t] = c;
        __syncthreads();
        for (int off = 1; off < 256; off <<= 1) {
            int v = (t >= off) ? sb[t - off] : 0;
            __syncthreads();
            sb[t] += v;
            __syncthreads();
        }
        if (t < CH && i < n) rowptr[i] = boff + sb[t] - c;
        if (i == n) rowptr[n] = E;   // duplicate writes of same value are benign
    }
    grid.sync();

    // phase 4: place edges (atomic-free) + degree histogram
    for (int i = gtid; i < E; i += T) {
        int p = rowptr[dst[i]] + rank[i];
        edge_p[p] = ((unsigned)f2bf(ew[i]) << 16) | (unsigned)src[i];
    }
    for (int i = gtid; i < n; i += T) {
        int d = counts[i * 16];
        d = (d > DMAX) ? DMAX : d;
        atomicAdd(&deghist[d * 16], 1);
    }
    grid.sync();

    // phase 5: bucket exclusive bases (redundant per block) + scatter perm
    {
        int v = (t <= DMAX) ? deghist[t * 16] : 0;
        __syncthreads();
        sb[t] = v;
        __syncthreads();
        for (int off = 1; off < 256; off <<= 1) {
            int x = (t >= off) ? sb[t - off] : 0;
            __syncthreads();
            sb[t] += x;
            __syncthreads();
        }
        int excl = sb[t] - v;
        __syncthreads();
        sb[t] = excl;
        __syncthreads();
        for (int i = gtid; i < n; i += T) {
            int d = counts[i * 16];
            d = (d > DMAX) ? DMAX : d;
            int pos = sb[d] + atomicAdd(&dcur[d * 16], 1);
            perm[pos] = i;
        }
    }
}

// ---------------- MFMA GEMM + fused el/er + bf16 ft output ----------------
// A32: A is fp32 [n][128] (converted during staging); else bf16 packed rows.

template <int NT, int H, bool A32>
__global__ __launch_bounds__(256) void gemm_mfma(const void* __restrict__ Ap,
                                                 const unsigned short* __restrict__ Wt,
                                                 const float* __restrict__ al,
                                                 const float* __restrict__ ar,
                                                 unsigned short* __restrict__ ftb,
                                                 float* __restrict__ el,
                                                 float* __restrict__ er, int n) {
    constexpr int LDA = 136;  // bf16 elems per LDS row (128 + 8 pad)
    constexpr int D = NT * 16 / H;
    __shared__ unsigned short As[64 * LDA];
    __shared__ unsigned short Ws[NT * 16 * LDA];
    int t = threadIdx.x;
    int row0 = blockIdx.x * 64;

    if constexpr (A32) {
        const float4* A4 = (const float4*)Ap;
        #pragma unroll
        for (int j = 0; j < 8; ++j) {
            int idx = t + j * 256;
            int r = idx >> 5;
            int c4 = idx & 31;
            int row = row0 + r;
            float4 v = (row < n) ? A4[(size_t)row * 32 + c4] : make_float4(0.f, 0.f, 0.f, 0.f);
            unsigned p0 = (unsigned)f2bf(v.x) | ((unsigned)f2bf(v.y) << 16);
            unsigned p1 = (unsigned)f2bf(v.z) | ((unsigned)f2bf(v.w) << 16);
            *(uint2*)&As[r * LDA + c4 * 4] = make_uint2(p0, p1);
        }
    } else {
        const uint4* A16 = (const uint4*)Ap;
        #pragma unroll
        for (int j = 0; j < 4; ++j) {
            int idx = t + j * 256;
            int r = idx >> 4;
            int c8 = idx & 15;
            int row = row0 + r;
            uint4 v = (row < n) ? A16[(size_t)row * 16 + c8] : make_uint4(0, 0, 0, 0);
            *(uint4*)&As[r * LDA + c8 * 8] = v;
        }
    }
    const uint4* Wg = (const uint4*)Wt;
    #pragma unroll
    for (int j = 0; j < NT; ++j) {
        int idx = t + j * 256;
        int r = idx >> 4;
        int c8 = idx & 15;
        *(uint4*)&Ws[r * LDA + c8 * 8] = Wg[idx];
    }
    __syncthreads();

    int w = t >> 6, lane = t & 63;
    int m = lane & 15, q = lane >> 4;
    f32x4 acc[NT] = {};
    const unsigned short* ap = &As[(w * 16 + m) * LDA + q * 8];
    #pragma unroll
    for (int kk = 0; kk < 4; ++kk) {
        bf16x8 a = *(const bf16x8*)(ap + kk * 32);
        #pragma unroll
        for (int nt = 0; nt < NT; ++nt) {
            bf16x8 b = *(const bf16x8*)&Ws[(nt * 16 + m) * LDA + kk * 32 + q * 8];
            acc[nt] = __builtin_amdgcn_mfma_f32_16x16x32_bf16(a, b, acc[nt], 0, 0, 0);
        }
    }

    float alv[NT], arv[NT];
    #pragma unroll
    for (int nt = 0; nt < NT; ++nt) {
        alv[nt] = al[nt * 16 + m];
        arv[nt] = ar[nt * 16 + m];
    }

    int orow = row0 + w * 16 + q * 4;
    #pragma unroll
    for (int r = 0; r < 4; ++r) {
        int row = orow + r;
        float pl[H] = {}, pr[H] = {};
        #pragma unroll
        for (int nt = 0; nt < NT; ++nt) {
            int h = (nt * 16) / D;
            pl[h] = fmaf(acc[nt][r], alv[nt], pl[h]);
            pr[h] = fmaf(acc[nt][r], arv[nt], pr[h]);
        }
        #pragma unroll
        for (int off = 1; off < 16; off <<= 1) {
            #pragma unroll
            for (int h = 0; h < H; ++h) {
                pl[h] += __shfl_xor(pl[h], off, 64);
                pr[h] += __shfl_xor(pr[h], off, 64);
            }
        }
        if (row < n) {
            #pragma unroll
            for (int nt = 0; nt < NT; ++nt)
                ftb[(size_t)row * (NT * 16) + nt * 16 + m] = f2bf(acc[nt][r]);
            if (m < H) {
                float vl = pl[0], vr = pr[0];
                #pragma unroll
                for (int h = 1; h < H; ++h)
                    if (m == h) { vl = pl[h]; vr = pr[h]; }
                el[row * H + m] = vl;
                er[row * H + m] = vr;
            }
        }
    }
}

// ---------------- fused GAT aggregate + ELU + LayerNorm + residual ----------------
// 4 nodes/wave (degree-sorted via perm -> uniform edge loops), 16 lanes/node,
// 8 dims/lane; x4-batched gathers. PREV32: residual input fp32 (layer 0).

__device__ inline void accum8(float* ax, uint4 u, float p) {
    ax[0] = fmaf(p, __uint_as_float(u.x << 16), ax[0]);
    ax[1] = fmaf(p, __uint_as_float(u.x & 0xFFFF0000u), ax[1]);
    ax[2] = fmaf(p, __uint_as_float(u.y << 16), ax[2]);
    ax[3] = fmaf(p, __uint_as_float(u.y & 0xFFFF0000u), ax[3]);
    ax[4] = fmaf(p, __uint_as_float(u.z << 16), ax[4]);
    ax[5] = fmaf(p, __uint_as_float(u.z & 0xFFFF0000u), ax[5]);
    ax[6] = fmaf(p, __uint_as_float(u.w << 16), ax[6]);
    ax[7] = fmaf(p, __uint_as_float(u.w & 0xFFFF0000u), ax[7]);
}

template <bool PREV32>
__global__ __launch_bounds__(256) void gat_agg_ln(
    const int* __restrict__ perm, const int* __restrict__ rowptr,
    const unsigned* __restrict__ edge_p, const uint4* __restrict__ ftb4,
    const float* __restrict__ el, const float* __restrict__ er,
    const float* __restrict__ lam_p, const float* __restrict__ g,
    const float* __restrict__ b, const void* __restrict__ prevp,
    uint4* __restrict__ outb, int n) {
    int gidx = blockIdx.x * 16 + (threadIdx.x >> 4);
    if (gidx >= n) return;
    int node = perm[gidx];
    int li = threadIdx.x & 15;
    int head = li >> 2;
    float lam = lam_p[0];
    float erv = er[node * 4 + head];
    int s0 = rowptr[node], s1 = rowptr[node + 1];
    float ax[8] = {};
    float s = 0.f;

    int i = s0;
    for (; i + 4 <= s1; i += 4) {
        unsigned e0 = edge_p[i], e1 = edge_p[i + 1], e2 = edge_p[i + 2], e3 = edge_p[i + 3];
        unsigned sn0 = e0 & 0xFFFFu, sn1 = e1 & 0xFFFFu, sn2 = e2 & 0xFFFFu, sn3 = e3 & 0xFFFFu;
        uint4 u0 = ftb4[(size_t)sn0 * 16 + li];
        uint4 u1 = ftb4[(size_t)sn1 * 16 + li];
        uint4 u2 = ftb4[(size_t)sn2 * 16 + li];
        uint4 u3 = ftb4[(size_t)sn3 * 16 + li];
        float l0 = el[sn0 * 4 + head];
        float l1 = el[sn1 * 4 + head];
        float l2 = el[sn2 * 4 + head];
        float l3 = el[sn3 * 4 + head];
        float v0 = l0 + erv + lam * __uint_as_float(e0 & 0xFFFF0000u);
        float v1 = l1 + erv + lam * __uint_as_float(e1 & 0xFFFF0000u);
        float v2 = l2 + erv + lam * __uint_as_float(e2 & 0xFFFF0000u);
        float v3 = l3 + erv + lam * __uint_as_float(e3 & 0xFFFF0000u);
        v0 = fmaxf(v0, NEG_SLOPE * v0);
        v1 = fmaxf(v1, NEG_SLOPE * v1);
        v2 = fmaxf(v2, NEG_SLOPE * v2);
        v3 = fmaxf(v3, NEG_SLOPE * v3);
        float p0 = __expf(v0), p1 = __expf(v1), p2 = __expf(v2), p3 = __expf(v3);
        accum8(ax, u0, p0);
        accum8(ax, u1, p1);
        accum8(ax, u2, p2);
        accum8(ax, u3, p3);
        s += (p0 + p1) + (p2 + p3);
    }
    for (; i < s1; ++i) {
        unsigned e = edge_p[i];
        unsigned sn = e & 0xFFFFu;
        uint4 u = ftb4[(size_t)sn * 16 + li];
        float v = el[sn * 4 + head] + erv + lam * __uint_as_float(e & 0xFFFF0000u);
        v = fmaxf(v, NEG_SLOPE * v);
        float p = __expf(v);
        accum8(ax, u, p);
        s += p;
    }

    float inv = (s > 0.f) ? 1.f / s : 0.f;
    float x[8];
    float sum = 0.f, sq = 0.f;
    #pragma unroll
    for (int d = 0; d < 8; ++d) {
        float v = ax[d] * inv;
        v = (v > 0.f) ? v : expm1f(v);
        x[d] = v;
        sum += v;
        sq += v * v;
    }
    #pragma unroll
    for (int off = 1; off < 16; off <<= 1) {
        sum += __shfl_xor(sum, off, 16);
        sq += __shfl_xor(sq, off, 16);
    }
    float mu = sum * (1.f / 128.f);
    float var = sq * (1.f / 128.f) - mu * mu;
    float rs = rsqrtf(var + LN_EPS);

    const float4* g4 = (const float4*)g;
    const float4* b4 = (const float4*)b;
    float pv[8];
    if constexpr (PREV32) {
        const float4* p4 = (const float4*)prevp;
        #pragma unroll
        for (int h = 0; h < 2; ++h) {
            float4 v = p4[(size_t)node * 32 + li * 2 + h];
            pv[h * 4 + 0] = v.x; pv[h * 4 + 1] = v.y;
            pv[h * 4 + 2] = v.z; pv[h * 4 + 3] = v.w;
        }
    } else {
        unpack8(((const uint4*)prevp)[(size_t)node * 16 + li], pv);
    }
    float y[8];
    #pragma unroll
    for (int h = 0; h < 2; ++h) {
        float4 gv = g4[li * 2 + h];
        float4 bv = b4[li * 2 + h];
        y[h * 4 + 0] = (x[h * 4 + 0] - mu) * rs * gv.x + bv.x + pv[h * 4 + 0];
        y[h * 4 + 1] = (x[h * 4 + 1] - mu) * rs * gv.y + bv.y + pv[h * 4 + 1];
        y[h * 4 + 2] = (x[h * 4 + 2] - mu) * rs * gv.z + bv.z + pv[h * 4 + 2];
        y[h * 4 + 3] = (x[h * 4 + 3] - mu) * rs * gv.w + bv.w + pv[h * 4 + 3];
    }
    uint4 o;
    o.x = (unsigned)f2bf(y[0]) | ((unsigned)f2bf(y[1]) << 16);
    o.y = (unsigned)f2bf(y[2]) | ((unsigned)f2bf(y[3]) << 16);
    o.z = (unsigned)f2bf(y[4]) | ((unsigned)f2bf(y[5]) << 16);
    o.w = (unsigned)f2bf(y[6]) | ((unsigned)f2bf(y[7]) << 16);
    outb[(size_t)node * 16 + li] = o;
}

// Layer 2: H=1, OUT=64; 4 nodes/wave (perm), 16 lanes/node, 4 dims/lane, x4 batch.
__global__ __launch_bounds__(256) void gat_agg_out(
    const int* __restrict__ perm, const int* __restrict__ rowptr,
    const unsigned* __restrict__ edge_p, const uint2* __restrict__ ftb2,
    const float* __restrict__ el, const float* __restrict__ er,
    const float* __restrict__ lam_p, float* __restrict__ out, int n) {
    int gidx = blockIdx.x * 16 + (threadIdx.x >> 4);
    if (gidx >= n) return;
    int node = perm[gidx];
    int li = threadIdx.x & 15;
    float lam = lam_p[0];
    float erv = er[node];
    int s0 = rowptr[node], s1 = rowptr[node + 1];
    float ax[4] = {};
    float s = 0.f;

    int i = s0;
    for (; i + 4 <= s1; i += 4) {
        unsigned e0 = edge_p[i], e1 = edge_p[i + 1], e2 = edge_p[i + 2], e3 = edge_p[i + 3];
        unsigned sn0 = e0 & 0xFFFFu, sn1 = e1 & 0xFFFFu, sn2 = e2 & 0xFFFFu, sn3 = e3 & 0xFFFFu;
        uint2 u0 = ftb2[(size_t)sn0 * 16 + li];
        uint2 u1 = ftb2[(size_t)sn1 * 16 + li];
        uint2 u2 = ftb2[(size_t)sn2 * 16 + li];
        uint2 u3 = ftb2[(size_t)sn3 * 16 + li];
        float l0 = el[sn0], l1 = el[sn1], l2 = el[sn2], l3 = el[sn3];
        float v0 = l0 + erv + lam * __uint_as_float(e0 & 0xFFFF0000u);
        float v1 = l1 + erv + lam * __uint_as_float(e1 & 0xFFFF0000u);
        float v2 = l2 + erv + lam * __uint_as_float(e2 & 0xFFFF0000u);
        float v3 = l3 + erv + lam * __uint_as_float(e3 & 0xFFFF0000u);
        v0 = fmaxf(v0, NEG_SLOPE * v0);
        v1 = fmaxf(v1, NEG_SLOPE * v1);
        v2 = fmaxf(v2, NEG_SLOPE * v2);
        v3 = fmaxf(v3, NEG_SLOPE * v3);
        float p0 = __expf(v0), p1 = __expf(v1), p2 = __expf(v2), p3 = __expf(v3);
        ax[0] = fmaf(p0, __uint_as_float(u0.x << 16), ax[0]);
        ax[1] = fmaf(p0, __uint_as_float(u0.x & 0xFFFF0000u), ax[1]);
        ax[2] = fmaf(p0, __uint_as_float(u0.y << 16), ax[2]);
        ax[3] = fmaf(p0, __uint_as_float(u0.y & 0xFFFF0000u), ax[3]);
        ax[0] = fmaf(p1, __uint_as_float(u1.x << 16), ax[0]);
        ax[1] = fmaf(p1, __uint_as_float(u1.x & 0xFFFF0000u), ax[1]);
        ax[2] = fmaf(p1, __uint_as_float(u1.y << 16), ax[2]);
        ax[3] = fmaf(p1, __uint_as_float(u1.y & 0xFFFF0000u), ax[3]);
        ax[0] = fmaf(p2, __uint_as_float(u2.x << 16), ax[0]);
        ax[1] = fmaf(p2, __uint_as_float(u2.x & 0xFFFF0000u), ax[1]);
        ax[2] = fmaf(p2, __uint_as_float(u2.y << 16), ax[2]);
        ax[3] = fmaf(p2, __uint_as_float(u2.y & 0xFFFF0000u), ax[3]);
        ax[0] = fmaf(p3, __uint_as_float(u3.x << 16), ax[0]);
        ax[1] = fmaf(p3, __uint_as_float(u3.x & 0xFFFF0000u), ax[1]);
        ax[2] = fmaf(p3, __uint_as_float(u3.y << 16), ax[2]);
        ax[3] = fmaf(p3, __uint_as_float(u3.y & 0xFFFF0000u), ax[3]);
        s += (p0 + p1) + (p2 + p3);
    }
    for (; i < s1; ++i) {
        unsigned e = edge_p[i];
        unsigned sn = e & 0xFFFFu;
        uint2 u = ftb2[(size_t)sn * 16 + li];
        float v = el[sn] + erv + lam * __uint_as_float(e & 0xFFFF0000u);
        v = fmaxf(v, NEG_SLOPE * v);
        float p = __expf(v);
        ax[0] = fmaf(p, __uint_as_float(u.x << 16), ax[0]);
        ax[1] = fmaf(p, __uint_as_float(u.x & 0xFFFF0000u), ax[1]);
        ax[2] = fmaf(p, __uint_as_float(u.y << 16), ax[2]);
        ax[3] = fmaf(p, __uint_as_float(u.y & 0xFFFF0000u), ax[3]);
        s += p;
    }

    float inv = (s > 0.f) ? 1.f / s : 0.f;
    float4 y;
    y.x = ax[0] * inv;
    y.y = ax[1] * inv;
    y.z = ax[2] * inv;
    y.w = ax[3] * inv;
    ((float4*)out)[(size_t)node * 16 + li] = y;
    ((float4*)out)[(size_t)(n + node) * 16 + li] = y;
}

// ---------------- launch ----------------

extern "C" void kernel_launch(void* const* d_in, const int* in_sizes, int n_in,
                              void* d_out, int out_size, void* d_ws, size_t ws_size,
                              hipStream_t stream) {
    const float* features = (const float*)d_in[0];
    const float* edge_weight = (const float*)d_in[1];
    const int* src = (const int*)d_in[2];
    const int* dst = (const int*)d_in[3];
    const float* W0 = (const float*)d_in[4];
    const float* al0 = (const float*)d_in[5];
    const float* ar0 = (const float*)d_in[6];
    const float* lam0 = (const float*)d_in[7];
    const float* W1 = (const float*)d_in[8];
    const float* al1 = (const float*)d_in[9];
    const float* ar1 = (const float*)d_in[10];
    const float* lam1 = (const float*)d_in[11];
    const float* W2 = (const float*)d_in[12];
    const float* al2 = (const float*)d_in[13];
    const float* ar2 = (const float*)d_in[14];
    const float* lam2 = (const float*)d_in[15];
    const float* g0 = (const float*)d_in[16];
    const float* b0 = (const float*)d_in[17];
    const float* g1 = (const float*)d_in[18];
    const float* b1 = (const float*)d_in[19];

    int N = in_sizes[0] / 128;   // 50000 (< 65536: src fits 16 bits)
    int E = in_sizes[1];

    char* w = (char*)d_ws;
    size_t o = 0;
    auto carve = [&](size_t bytes) {
        char* p = w + o;
        o += (bytes + 255) & ~(size_t)255;
        return p;
    };
    int* counts = (int*)carve((size_t)N * 64);       // 1 counter per 64B line
    int* rowptr = (int*)carve((size_t)(N + 1) * 4);
    int* bsum = (int*)carve(CGRID * 4);
    int* rank = (int*)carve((size_t)E * 4);
    unsigned* edge_p = (unsigned*)carve((size_t)E * 4);
    int* deghist = (int*)carve((DMAX + 1) * 64);
    int* dcur = (int*)carve((DMAX + 1) * 64);
    int* perm = (int*)carve((size_t)N * 4);
    unsigned short* ftb = (unsigned short*)carve((size_t)N * 128 * 2);
    unsigned short* h1 = (unsigned short*)carve((size_t)N * 128 * 2);
    unsigned short* h2 = (unsigned short*)carve((size_t)N * 128 * 2);
    float* el = (float*)carve((size_t)N * 4 * 4);
    float* er = (float*)carve((size_t)N * 4 * 4);
    unsigned short* Wt0 = (unsigned short*)carve(128 * 128 * 2);
    unsigned short* Wt1 = (unsigned short*)carve(128 * 128 * 2);
    unsigned short* Wt2 = (unsigned short*)carve(64 * 128 * 2);

    const int ngemm = (N + 63) / 64;
    const int nagg = (N + 15) / 16;

    // one cooperative launch: CSR build + degree-sort perm + W transposes
    void* args[] = {(void*)&src, (void*)&dst, (void*)&edge_weight, (void*)&counts,
                    (void*)&rank, (void*)&bsum, (void*)&rowptr, (void*)&edge_p,
                    (void*)&deghist, (void*)&dcur, (void*)&perm, (void*)&N, (void*)&E,
                    (void*)&W0, (void*)&W1, (void*)&W2, (void*)&Wt0, (void*)&Wt1,
                    (void*)&Wt2};
    hipLaunchCooperativeKernel((void*)csr_coop, dim3(CGRID), dim3(256), args, 0, stream);

    // Layer 0 (fp32 A, fp32 residual)
    gemm_mfma<8, 4, true><<<ngemm, 256, 0, stream>>>(features, Wt0, al0, ar0,
                                                     ftb, el, er, N);
    gat_agg_ln<true><<<nagg, 256, 0, stream>>>(perm, rowptr, edge_p, (const uint4*)ftb,
                                               el, er, lam0, g0, b0, features,
                                               (uint4*)h1, N);
    // Layer 1
    gemm_mfma<8, 4, false><<<ngemm, 256, 0, stream>>>(h1, Wt1, al1, ar1, ftb, el, er, N);
    gat_agg_ln<false><<<nagg, 256, 0, stream>>>(perm, rowptr, edge_p, (const uint4*)ftb,
                                                el, er, lam1, g1, b1, h1, (uint4*)h2, N);
    // Layer 2
    gemm_mfma<4, 1, false><<<ngemm, 256, 0, stream>>>(h2, Wt2, al2, ar2, ftb, el, er, N);
    gat_agg_out<<<nagg, 256, 0, stream>>>(perm, rowptr, edge_p, (const uint2*)ftb,
                                          el, er, lam2, (float*)d_out, N);
}